// Round 7
// baseline (210.398 us; speedup 1.0000x reference)
//
#include <hip/hip_runtime.h>

// Causal SDPA, B=16, N=4096, DK=DV=64, fp32 in/out. R16 = R15 with the q-tile
// DOUBLED to 128 rows (8 waves/block, wq 0..3 x wk 0..1) to HALVE staging
// traffic. R11..R15 post-mortem: kernel is staging-bound -- both R11 and R15
// move 533 MB through global_load_lds at ~10-12 B/cyc/CU (the per-CU VMEM
// path ceiling); compute cuts (28->10 MFMAs) changed nothing. 128-row tiles
// amortize each 16 KB k-tile over 2x output rows: 533 -> 270 MB staged.
//  - inner per-wave compute byte-identical to R15 (32q x 32k quadrant,
//    10x mfma_f32_32x32x16_bf16, K-row-permuted P->A identity, exp2 softmax,
//    V 16B-granule image); mask uses global q/k indices.
//  - schedule: per queue r (2 batches), 16 pairs: shallow tile j (2j+2
//    k-tiles) + deep tile 31-j (64-2j); role A = shallow full + deep head
//    (33 total), role B = deep tail (33). 512 blocks x 512 thr = 2/CU.
//  - cross-wk reduction uses the full 32 KB smem + 512 B lredX; partials
//    for deep tiles 16..31 (wsO/wsL layout sizes unchanged).
//  - counted-vmcnt two-barrier pipeline kept (2 loads/wave/k-tile -> vmcnt(2)).

#define N_SEQ 4096
#define DIM   64

typedef __bf16  bf16x8 __attribute__((ext_vector_type(8)));
typedef unsigned short u16x8 __attribute__((ext_vector_type(8)));
typedef float   f32x4  __attribute__((ext_vector_type(4)));
typedef float   f32x16 __attribute__((ext_vector_type(16)));

static __device__ __forceinline__ unsigned short f2bf(float f) {
    unsigned int u = __float_as_uint(f);
    u += 0x7FFFu + ((u >> 16) & 1u);   // RNE
    return (unsigned short)(u >> 16);
}

static __device__ __forceinline__ unsigned int pk2bf(float a, float b) {
#if defined(__HIP_DEVICE_COMPILE__) && __has_builtin(__builtin_amdgcn_cvt_pk_bf16_f32)
    typedef __bf16 bf16x2_t __attribute__((ext_vector_type(2)));
    bf16x2_t r = __builtin_amdgcn_cvt_pk_bf16_f32(a, b);
    return __builtin_bit_cast(unsigned int, r);
#else
    return (unsigned int)f2bf(a) | ((unsigned int)f2bf(b) << 16);
#endif
}

static __device__ __forceinline__ float fexp2(float x) {
#if defined(__HIP_DEVICE_COMPILE__) && __has_builtin(__builtin_amdgcn_exp2f)
    return __builtin_amdgcn_exp2f(x);
#else
    return exp2f(x);
#endif
}

static __device__ __forceinline__ bf16x8 ld_frag(const void* p) {
    u16x8 u = *reinterpret_cast<const u16x8*>(p);  // ds_read_b128
    return __builtin_bit_cast(bf16x8, u);
}

// 32x32x16 bf16 MFMA: A,B = 8 bf16/lane (4 VGPR), C/D = 16 f32/lane.
static __device__ __forceinline__ f32x16 mfma32(bf16x8 a, bf16x8 b, f32x16 c) {
#if defined(__HIP_DEVICE_COMPILE__)
#if __has_builtin(__builtin_amdgcn_mfma_f32_32x32x16_bf16)
    return __builtin_amdgcn_mfma_f32_32x32x16_bf16(a, b, c, 0, 0, 0);
#else
    f32x16 d;
    asm volatile("v_mfma_f32_32x32x16_bf16 %0, %1, %2, %3"
                 : "=v"(d) : "v"(a), "v"(b), "v"(c));
    return d;
#endif
#else
    (void)a; (void)b;
    return c;
#endif
}

static __device__ __forceinline__ void gl_lds16(const unsigned short* g, unsigned short* l) {
#if defined(__HIP_DEVICE_COMPILE__)
    __builtin_amdgcn_global_load_lds(
        (const __attribute__((address_space(1))) unsigned int*)(g),
        (__attribute__((address_space(3))) unsigned int*)(l), 16, 0, 0);
#else
    (void)g; (void)l;
#endif
}

// ---- fused pre-pass: z=0: K image (rows bit2<->3 permuted); z=1: V^T image ----
// (UNCHANGED from R13-R15: images are per-64-row k-tile, independent of q-tiling)
__global__ __launch_bounds__(256)
void prep_kv(const float* __restrict__ K, const float* __restrict__ V,
             unsigned short* __restrict__ wsK, unsigned short* __restrict__ wsV) {
    const int b = blockIdx.y, t = blockIdx.x;
    if (blockIdx.z == 0) {
        const float* src = K + ((size_t)b * N_SEQ + t * 64) * DIM;
        unsigned short* dst = wsK + ((size_t)(b * 64 + t)) * 4096;
        #pragma unroll
        for (int ph = 0; ph < 2; ++ph) {
            const int gidx = threadIdx.x + ph * 256;
            const int r = gidx >> 3, g = gidx & 7;     // r = actual kpos, g = dk octet
            const float* p = src + r * DIM + g * 8;
            f32x4 f0 = *reinterpret_cast<const f32x4*>(p);
            f32x4 f1 = *reinterpret_cast<const f32x4*>(p + 4);
            uint4 w;
            w.x = pk2bf(f0[0], f0[1]); w.y = pk2bf(f0[2], f0[3]);
            w.z = pk2bf(f1[0], f1[1]); w.w = pk2bf(f1[2], f1[3]);
            // image row = r with bits 2,3 swapped (involution)
            const int rp = (r & 51) | ((r & 4) << 1) | ((r & 8) >> 1);
            *reinterpret_cast<uint4*>(&dst[(rp * 8 + (g ^ (rp & 7))) * 8]) = w;
        }
    } else {
        // V^T image: row dv (64 kpos bf16 = 128 B = 8 granules of 8 bf16).
        // Granule (c ^ (dv&7)) of row dv holds kpos octet c*8..c*8+7.
        const int dv = threadIdx.x & 63;
        const int g0 = threadIdx.x >> 6;               // 0..3
        const float* src = V + ((size_t)b * N_SEQ + t * 64) * DIM + dv;
        unsigned short* dst = wsV + ((size_t)(b * 64 + t)) * 4096 + dv * 64;
        #pragma unroll
        for (int ph = 0; ph < 2; ++ph) {
            const int c = g0 * 2 + ph;                 // content octet 0..7
            float p[8];
            #pragma unroll
            for (int e = 0; e < 8; ++e)
                p[e] = src[(size_t)(c * 8 + e) * DIM]; // coalesced over dv
            uint4 w;
            w.x = pk2bf(p[0], p[1]); w.y = pk2bf(p[2], p[3]);
            w.z = pk2bf(p[4], p[5]); w.w = pk2bf(p[6], p[7]);
            *reinterpret_cast<uint4*>(&dst[(c ^ (dv & 7)) * 8]) = w;
        }
    }
}

// ---- main: flash attention, 128-row q-tiles, static split-K, 32x32 MFMAs ----
__global__ __launch_bounds__(512, 1)
void attn_fwd(const float* __restrict__ Q, const unsigned short* __restrict__ wsK,
              const unsigned short* __restrict__ wsV, float* __restrict__ O,
              float* __restrict__ wsO, float* __restrict__ wsL) {
    // smem layout (u16): [0,4096)=K buf0, [4096,8192)=K buf1,
    //                    [8192,12288)=V buf0, [12288,16384)=V buf1  (32 KB)
    __shared__ unsigned short smem[16384];
    __shared__ float lredX[128];               // wk=1 row sums (512 B)

    const int tid  = threadIdx.x;
    const int wave = tid >> 6;                 // 0..7
    const int lane = tid & 63;
    const int l31  = lane & 31;
    const int h    = lane >> 5;                // half-wave
    const int l7   = lane & 7;
    const int wq   = wave & 3;                 // q quarter (rows wq*32..+32)
    const int wk   = wave >> 2;                // kpos-half (kpos wk*32..+32)

    const int L    = (int)blockIdx.x;
    const int r    = L & 7;                    // XCD queue (batches {2r,2r+1})
    const int w    = L >> 3;                   // worker 0..63
    const int role = w & 1;                    // 0=A, 1=B
    const int bsel = (w >> 1) & 1;
    const int j    = w >> 2;                   // pair index 0..15
    const int b    = r * 2 + bsel;
    const int Tq   = 31 - j;                   // deep q-tile (depth 64-2j k-tiles)

    // item list (<=2): {tile, kt0, kt1, partial(half)}; depths: 2j+2 / 64-2j
    int it_tile[2], it_k0[2], it_k1[2], it_half[2], n_items;
    if (role == 0) {                   // A: shallow tile full + deep head
        it_tile[0] = j;   it_k0[0] = 0;          it_k1[0] = 2 * j + 2;  it_half[0] = -1;
        it_tile[1] = Tq;  it_k0[1] = 0;          it_k1[1] = 31 - 2 * j; it_half[1] = 0;
        n_items = 2;                   // (2j+2)+(31-2j) = 33
    } else {                           // B: deep tail (33 k-tiles, incl. diagonal)
        it_tile[0] = Tq;  it_k0[0] = 31 - 2 * j; it_k1[0] = 64 - 2 * j; it_half[0] = 1;
        n_items = 1;
    }

    // loop-invariant LDS byte addresses (within an 8 KB K / V buffer)
    int kaddr[4];   // [s]: K A-frag, image row wk*32+l31, granule (s*2+h)^l7
    #pragma unroll
    for (int s = 0; s < 4; ++s)
        kaddr[s] = (wk * 32 + l31) * 128 + (((s * 2 + h) ^ l7) * 16);
    int vbase[2];   // [t]: V B-frag, row l31 (+dvt*4096B), granule (wk*4+t*2+h)^l7
    #pragma unroll
    for (int t = 0; t < 2; ++t)
        vbase[t] = l31 * 128 + (((wk * 4 + t * 2 + h) ^ l7) * 16);

    const int dma_off = wave * 512 + lane * 8;        // u16; 16B/lane, 1KB/wave
    const u16x8 ones_u = {0x3F80, 0x3F80, 0x3F80, 0x3F80,
                          0x3F80, 0x3F80, 0x3F80, 0x3F80};
    const bf16x8 ones8 = __builtin_bit_cast(bf16x8, ones_u);
    const float QS = 0.125f * 1.44269504f;            // scale * log2(e)

    const unsigned short* kt_src = wsK + (size_t)b * 64 * 4096;
    const unsigned short* vt_src = wsV + (size_t)b * 64 * 4096;

    for (int it = 0; it < n_items; ++it) {
        const int tt    = it_tile[it];
        const int kt0   = it_k0[it];
        const int kt1   = it_k1[it];
        const int half  = it_half[it];
        const int i0    = tt * 128;            // q-tile base row
        const int tdiag = 2 * tt;              // first k-tile needing mask

        __syncthreads();                 // LDS free from previous item

        f32x16 o_acc[2] = {};  // [dvt]: D[q][dv], col dv=dvt*32+l31, rows q-pattern
        f32x16 lones = {};     // row sums via ones-MFMA

        if (kt0 < kt1) {
            // Q fragments (B-operand): lane = q row i0+wq*32+l31, k = s*16+h*8+jj
            u16x8 qb[4];
            const float* qptr = Q + ((size_t)b * N_SEQ + i0 + wq * 32 + l31) * DIM;
            #pragma unroll
            for (int s = 0; s < 4; ++s) {
                const float* p = qptr + s * 16 + h * 8;
                f32x4 f0 = *reinterpret_cast<const f32x4*>(p);
                f32x4 f1 = *reinterpret_cast<const f32x4*>(p + 4);
                #pragma unroll
                for (int jj = 0; jj < 4; ++jj) {
                    qb[s][jj]     = f2bf(f0[jj] * QS);
                    qb[s][4 + jj] = f2bf(f1[jj] * QS);
                }
            }

            auto dma = [&](int kt, int bufi) {        // 16 KB k-tile, 2 loads/wave
                gl_lds16(kt_src + (size_t)kt * 4096 + dma_off,
                         &smem[bufi * 4096 + dma_off]);
                gl_lds16(vt_src + (size_t)kt * 4096 + dma_off,
                         &smem[8192 + bufi * 4096 + dma_off]);
            };

            auto compute = [&](int kt, const unsigned short* kb, const unsigned short* vb) {
                // S^T quadrant = K(wk-half, row-permuted) * Q^T(wq quarter)
                f32x16 st = {};
                #pragma unroll
                for (int s = 0; s < 4; ++s) {
                    bf16x8 kf = ld_frag((const char*)kb + kaddr[s]);
                    st = mfma32(kf, __builtin_bit_cast(bf16x8, qb[s]), st);
                }
                // P = exp2(S^T) (+ causal mask on the 2 diagonal k-tiles)
                float pex[16];
                if (kt >= tdiag) {
                    const int qth = (i0 + wq * 32 + l31) - (kt * 64 + wk * 32 + 8 * h);
                    #pragma unroll
                    for (int rr = 0; rr < 16; ++rr) {
                        const int K0 = (rr & 7) | ((rr & 8) << 1);
                        pex[rr] = fexp2((K0 > qth) ? -3.0e38f : st[rr]);
                    }
                } else {
                    #pragma unroll
                    for (int rr = 0; rr < 16; ++rr)
                        pex[rr] = fexp2(st[rr]);
                }
                // reg order == PV A-layout k order (K row permutation):
                // A slice t = words u[4t..4t+3], kpos = wk*32 + 16t + 8h + (0..7)
                unsigned int u[8];
                #pragma unroll
                for (int g = 0; g < 4; ++g) {
                    u[2 * g]     = pk2bf(pex[4 * g],     pex[4 * g + 1]);
                    u[2 * g + 1] = pk2bf(pex[4 * g + 2], pex[4 * g + 3]);
                }
                // O += P V ; l += P * ones
                #pragma unroll
                for (int t = 0; t < 2; ++t) {
                    uint4 aw = make_uint4(u[4 * t], u[4 * t + 1], u[4 * t + 2], u[4 * t + 3]);
                    bf16x8 pa = __builtin_bit_cast(bf16x8, aw);
                    #pragma unroll
                    for (int dvt = 0; dvt < 2; ++dvt) {
                        bf16x8 bv = ld_frag((const char*)vb + vbase[t] + dvt * 4096);
                        o_acc[dvt] = mfma32(pa, bv, o_acc[dvt]);
                    }
                    lones = mfma32(pa, ones8, lones);
                }
            };

            dma(kt0, 0);
            int kt = kt0, bufi = 0;
            while (true) {
                // counted-vmcnt double-buffer pipeline (no vmcnt(0) drain)
                __builtin_amdgcn_s_barrier();          // all waves done READING buf^1
                __builtin_amdgcn_sched_barrier(0);
                if (kt + 1 < kt1) {
                    dma(kt + 1, bufi ^ 1);             // 2 loads, stay in flight
                    asm volatile("s_waitcnt vmcnt(2)" ::: "memory");  // kt's loads done
                } else {
                    asm volatile("s_waitcnt vmcnt(0)" ::: "memory");  // final tile
                }
                __builtin_amdgcn_sched_barrier(0);
                __builtin_amdgcn_s_barrier();          // kt staged data visible to all
                __builtin_amdgcn_sched_barrier(0);
                compute(kt, &smem[bufi * 4096], &smem[8192 + bufi * 4096]);
                if (++kt == kt1) break;
                bufi ^= 1;
            }
        }

        // ---- cross-wk reduction through the freed k-tile LDS (once per item) ----
        __syncthreads();                           // everyone done with smem
        float* red = reinterpret_cast<float*>(&smem[0]);   // 8192 f32 = 32 KB
        if (wk == 1) {
            #pragma unroll
            for (int rr = 0; rr < 16; ++rr) {
                const int qrow = (rr & 3) + 8 * (rr >> 2) + 4 * h;   // 0..31
                #pragma unroll
                for (int dvt = 0; dvt < 2; ++dvt)
                    red[wq * 2048 + qrow * 64 + dvt * 32 + l31] = o_acc[dvt][rr];
                if (l31 == 0) lredX[wq * 32 + qrow] = lones[rr];
            }
        }
        __syncthreads();
        if (wk == 0) {
            if (half < 0) {
                // final: normalize and write O directly
                float* obase = O + ((size_t)b * N_SEQ + i0 + wq * 32) * DIM;
                #pragma unroll
                for (int rr = 0; rr < 16; ++rr) {
                    const int qrow = (rr & 3) + 8 * (rr >> 2) + 4 * h;
                    const float lt = lones[rr] + lredX[wq * 32 + qrow];
                    const float inv = 1.0f / lt;
                    #pragma unroll
                    for (int dvt = 0; dvt < 2; ++dvt) {
                        const float val = o_acc[dvt][rr]
                            + red[wq * 2048 + qrow * 64 + dvt * 32 + l31];
                        obase[qrow * DIM + dvt * 32 + l31] = val * inv;
                    }
                }
            } else {
                // raw additive partial -> workspace (deep tiles 16..31)
                float* po = wsO + (((size_t)(b * 16 + (tt - 16)) * 2 + half) * 8192);
                float* pl = wsL + (((size_t)(b * 16 + (tt - 16)) * 2 + half) * 128);
                #pragma unroll
                for (int rr = 0; rr < 16; ++rr) {
                    const int qrow = (rr & 3) + 8 * (rr >> 2) + 4 * h;
                    const float lt = lones[rr] + lredX[wq * 32 + qrow];
                    #pragma unroll
                    for (int dvt = 0; dvt < 2; ++dvt)
                        po[(wq * 32 + qrow) * 64 + dvt * 32 + l31] = o_acc[dvt][rr]
                            + red[wq * 2048 + qrow * 64 + dvt * 32 + l31];
                    if (l31 == 0) pl[wq * 32 + qrow] = lt;
                }
            }
        }
        // next item's top-of-loop __syncthreads() protects smem/lredX reuse
    }
}

// ---- combine split-K partials for deep tiles 16..31 (128 rows each) ----
__global__ __launch_bounds__(256)
void norm_out(const float* __restrict__ wsO, const float* __restrict__ wsL,
              float* __restrict__ O) {
    const int t = 16 + blockIdx.x, b = blockIdx.y;
    const int row = threadIdx.x >> 1;            // 0..127
    const int c0  = (threadIdx.x & 1) * 32;      // 0,32
    const size_t base = (size_t)(b * 16 + (t - 16)) * 2;
    const float* p0 = wsO + base * 8192 + row * 64 + c0;
    const float* p1 = p0 + 8192;
    const float* l  = wsL + base * 128;
    const float inv = 1.0f / (l[row] + l[128 + row]);
    float* o = O + ((size_t)b * N_SEQ + t * 128 + row) * 64 + c0;
    #pragma unroll
    for (int i = 0; i < 32; i += 4) {
        f32x4 a = *reinterpret_cast<const f32x4*>(p0 + i);
        f32x4 c = *reinterpret_cast<const f32x4*>(p1 + i);
        f32x4 v = (a + c) * inv;
        *reinterpret_cast<f32x4*>(o + i) = v;
    }
}

extern "C" void kernel_launch(void* const* d_in, const int* in_sizes, int n_in,
                              void* d_out, int out_size, void* d_ws, size_t ws_size,
                              hipStream_t stream) {
    const float* q = (const float*)d_in[0];
    const float* k = (const float*)d_in[1];
    const float* v = (const float*)d_in[2];
    // d_in[3] = causal mask, analytic (tril) -- not read.
    float* out = (float*)d_out;

    unsigned short* wsK = (unsigned short*)d_ws;
    unsigned short* wsV = wsK + (size_t)16 * 64 * 4096;        // 8 MB each
    float* wsO = (float*)(wsV + (size_t)16 * 64 * 4096);       // 16.8 MB
    float* wsL = wsO + (size_t)16 * 16 * 2 * 8192;             // 0.26 MB

    prep_kv<<<dim3(64, 16, 2), dim3(256), 0, stream>>>(k, v, wsK, wsV);
    attn_fwd<<<dim3(512), dim3(512), 0, stream>>>(q, wsK, wsV, out, wsO, wsL);
    norm_out<<<dim3(16, 16), dim3(256), 0, stream>>>(wsO, wsL, out);
}

// Round 9
// 209.473 us; speedup vs baseline: 1.0044x; 1.0044x over previous
//
#include <hip/hip_runtime.h>

// Causal SDPA, B=16, N=4096, DK=DV=64, fp32 in/out. R18 = R17 resubmitted
// verbatim (R17 bench died with "MI355X container failed twice" = infra
// acquire failure, same signature as R10 which passed on resubmit; kernel
// re-audited: uniform barriers, exact vmcnt ladder, slot-overwrite fenced,
// all LDS/workspace bounds verified). R17 = R16 with the double-buffer
// DEEPENED to a 4-slot circular buffer (64 KB LDS) and prefetch lead raised
// 1 -> 3 k-tiles (vmcnt(6) steady state; tail 4->2->0).
// Theory: per-iteration wall ~6.4K cyc vs ~1.5-2K issue work => waves parked
// on DMA completion; 3-iteration lead (~15K cyc) covers multi-1000-cyc
// gl_lds latency+queueing. Occupancy unchanged (VGPR 116 caps at 2 blocks/CU;
// 2x64KB=128<=160KB).
// Carried from R16: 128-row q-tiles (8 waves, wq 0..3 x wk 0..1), 10x
// mfma_32x32x16 per wave-ktile, K-image row bit2<->3 permutation (QK C-reg
// order == PV A-k order), V 16B-granule image, exact static split-K
// schedule, cross-wk LDS reduction, P=exp2 static softmax.

#define N_SEQ 4096
#define DIM   64

typedef __bf16  bf16x8 __attribute__((ext_vector_type(8)));
typedef unsigned short u16x8 __attribute__((ext_vector_type(8)));
typedef float   f32x4  __attribute__((ext_vector_type(4)));
typedef float   f32x16 __attribute__((ext_vector_type(16)));

static __device__ __forceinline__ unsigned short f2bf(float f) {
    unsigned int u = __float_as_uint(f);
    u += 0x7FFFu + ((u >> 16) & 1u);   // RNE
    return (unsigned short)(u >> 16);
}

static __device__ __forceinline__ unsigned int pk2bf(float a, float b) {
#if defined(__HIP_DEVICE_COMPILE__) && __has_builtin(__builtin_amdgcn_cvt_pk_bf16_f32)
    typedef __bf16 bf16x2_t __attribute__((ext_vector_type(2)));
    bf16x2_t r = __builtin_amdgcn_cvt_pk_bf16_f32(a, b);
    return __builtin_bit_cast(unsigned int, r);
#else
    return (unsigned int)f2bf(a) | ((unsigned int)f2bf(b) << 16);
#endif
}

static __device__ __forceinline__ float fexp2(float x) {
#if defined(__HIP_DEVICE_COMPILE__) && __has_builtin(__builtin_amdgcn_exp2f)
    return __builtin_amdgcn_exp2f(x);
#else
    return exp2f(x);
#endif
}

static __device__ __forceinline__ bf16x8 ld_frag(const void* p) {
    u16x8 u = *reinterpret_cast<const u16x8*>(p);  // ds_read_b128
    return __builtin_bit_cast(bf16x8, u);
}

// 32x32x16 bf16 MFMA: A,B = 8 bf16/lane (4 VGPR), C/D = 16 f32/lane.
static __device__ __forceinline__ f32x16 mfma32(bf16x8 a, bf16x8 b, f32x16 c) {
#if defined(__HIP_DEVICE_COMPILE__)
#if __has_builtin(__builtin_amdgcn_mfma_f32_32x32x16_bf16)
    return __builtin_amdgcn_mfma_f32_32x32x16_bf16(a, b, c, 0, 0, 0);
#else
    f32x16 d;
    asm volatile("v_mfma_f32_32x32x16_bf16 %0, %1, %2, %3"
                 : "=v"(d) : "v"(a), "v"(b), "v"(c));
    return d;
#endif
#else
    (void)a; (void)b;
    return c;
#endif
}

static __device__ __forceinline__ void gl_lds16(const unsigned short* g, unsigned short* l) {
#if defined(__HIP_DEVICE_COMPILE__)
    __builtin_amdgcn_global_load_lds(
        (const __attribute__((address_space(1))) unsigned int*)(g),
        (__attribute__((address_space(3))) unsigned int*)(l), 16, 0, 0);
#else
    (void)g; (void)l;
#endif
}

// ---- fused pre-pass: z=0: K image (rows bit2<->3 permuted); z=1: V^T image ----
__global__ __launch_bounds__(256)
void prep_kv(const float* __restrict__ K, const float* __restrict__ V,
             unsigned short* __restrict__ wsK, unsigned short* __restrict__ wsV) {
    const int b = blockIdx.y, t = blockIdx.x;
    if (blockIdx.z == 0) {
        const float* src = K + ((size_t)b * N_SEQ + t * 64) * DIM;
        unsigned short* dst = wsK + ((size_t)(b * 64 + t)) * 4096;
        #pragma unroll
        for (int ph = 0; ph < 2; ++ph) {
            const int gidx = threadIdx.x + ph * 256;
            const int r = gidx >> 3, g = gidx & 7;     // r = actual kpos, g = dk octet
            const float* p = src + r * DIM + g * 8;
            f32x4 f0 = *reinterpret_cast<const f32x4*>(p);
            f32x4 f1 = *reinterpret_cast<const f32x4*>(p + 4);
            uint4 w;
            w.x = pk2bf(f0[0], f0[1]); w.y = pk2bf(f0[2], f0[3]);
            w.z = pk2bf(f1[0], f1[1]); w.w = pk2bf(f1[2], f1[3]);
            // image row = r with bits 2,3 swapped (involution)
            const int rp = (r & 51) | ((r & 4) << 1) | ((r & 8) >> 1);
            *reinterpret_cast<uint4*>(&dst[(rp * 8 + (g ^ (rp & 7))) * 8]) = w;
        }
    } else {
        // V^T image: row dv (64 kpos bf16 = 128 B = 8 granules of 8 bf16).
        // Granule (c ^ (dv&7)) of row dv holds kpos octet c*8..c*8+7.
        const int dv = threadIdx.x & 63;
        const int g0 = threadIdx.x >> 6;               // 0..3
        const float* src = V + ((size_t)b * N_SEQ + t * 64) * DIM + dv;
        unsigned short* dst = wsV + ((size_t)(b * 64 + t)) * 4096 + dv * 64;
        #pragma unroll
        for (int ph = 0; ph < 2; ++ph) {
            const int c = g0 * 2 + ph;                 // content octet 0..7
            float p[8];
            #pragma unroll
            for (int e = 0; e < 8; ++e)
                p[e] = src[(size_t)(c * 8 + e) * DIM]; // coalesced over dv
            uint4 w;
            w.x = pk2bf(p[0], p[1]); w.y = pk2bf(p[2], p[3]);
            w.z = pk2bf(p[4], p[5]); w.w = pk2bf(p[6], p[7]);
            *reinterpret_cast<uint4*>(&dst[(c ^ (dv & 7)) * 8]) = w;
        }
    }
}

// ---- main: flash attention, 128-row q-tiles, 4-deep prefetch pipeline ----
__global__ __launch_bounds__(512, 1)
void attn_fwd(const float* __restrict__ Q, const unsigned short* __restrict__ wsK,
              const unsigned short* __restrict__ wsV, float* __restrict__ O,
              float* __restrict__ wsO, float* __restrict__ wsL) {
    // smem (u16): K slots [0,16384) = 4 x 4096, V slots [16384,32768) = 4 x 4096.
    // 64 KB total. Epilogue aliases: red = f32[0..8191] (32 KB), lredX after.
    __shared__ unsigned short smem[32768];

    const int tid  = threadIdx.x;
    const int wave = tid >> 6;                 // 0..7
    const int lane = tid & 63;
    const int l31  = lane & 31;
    const int h    = lane >> 5;                // half-wave
    const int l7   = lane & 7;
    const int wq   = wave & 3;                 // q quarter (rows wq*32..+32)
    const int wk   = wave >> 2;                // kpos-half (kpos wk*32..+32)

    const int L    = (int)blockIdx.x;
    const int r    = L & 7;                    // XCD queue (batches {2r,2r+1})
    const int w    = L >> 3;                   // worker 0..63
    const int role = w & 1;                    // 0=A, 1=B
    const int bsel = (w >> 1) & 1;
    const int j    = w >> 2;                   // pair index 0..15
    const int b    = r * 2 + bsel;
    const int Tq   = 31 - j;                   // deep q-tile (depth 64-2j k-tiles)

    // item list (<=2): {tile, kt0, kt1, partial(half)}; depths: 2j+2 / 64-2j
    int it_tile[2], it_k0[2], it_k1[2], it_half[2], n_items;
    if (role == 0) {                   // A: shallow tile full + deep head
        it_tile[0] = j;   it_k0[0] = 0;          it_k1[0] = 2 * j + 2;  it_half[0] = -1;
        it_tile[1] = Tq;  it_k0[1] = 0;          it_k1[1] = 31 - 2 * j; it_half[1] = 0;
        n_items = 2;                   // (2j+2)+(31-2j) = 33
    } else {                           // B: deep tail (33 k-tiles, incl. diagonal)
        it_tile[0] = Tq;  it_k0[0] = 31 - 2 * j; it_k1[0] = 64 - 2 * j; it_half[0] = 1;
        n_items = 1;
    }

    // loop-invariant LDS byte addresses (within an 8 KB K / V slot)
    int kaddr[4];   // [s]: K A-frag, image row wk*32+l31, granule (s*2+h)^l7
    #pragma unroll
    for (int s = 0; s < 4; ++s)
        kaddr[s] = (wk * 32 + l31) * 128 + (((s * 2 + h) ^ l7) * 16);
    int vbase[2];   // [t]: V B-frag, row l31 (+dvt*4096B), granule (wk*4+t*2+h)^l7
    #pragma unroll
    for (int t = 0; t < 2; ++t)
        vbase[t] = l31 * 128 + (((wk * 4 + t * 2 + h) ^ l7) * 16);

    const int dma_off = wave * 512 + lane * 8;        // u16; 16B/lane, 1KB/wave
    const u16x8 ones_u = {0x3F80, 0x3F80, 0x3F80, 0x3F80,
                          0x3F80, 0x3F80, 0x3F80, 0x3F80};
    const bf16x8 ones8 = __builtin_bit_cast(bf16x8, ones_u);
    const float QS = 0.125f * 1.44269504f;            // scale * log2(e)

    const unsigned short* kt_src = wsK + (size_t)b * 64 * 4096;
    const unsigned short* vt_src = wsV + (size_t)b * 64 * 4096;

    for (int it = 0; it < n_items; ++it) {
        const int tt    = it_tile[it];
        const int kt0   = it_k0[it];
        const int kt1   = it_k1[it];
        const int half  = it_half[it];
        const int i0    = tt * 128;            // q-tile base row
        const int tdiag = 2 * tt;              // first k-tile needing mask

        __syncthreads();                 // LDS free from previous item

        f32x16 o_acc[2] = {};  // [dvt]: D[q][dv], col dv=dvt*32+l31, rows q-pattern
        f32x16 lones = {};     // row sums via ones-MFMA

        if (kt0 < kt1) {
            // Q fragments (B-operand): lane = q row i0+wq*32+l31, k = s*16+h*8+jj
            u16x8 qb[4];
            const float* qptr = Q + ((size_t)b * N_SEQ + i0 + wq * 32 + l31) * DIM;
            #pragma unroll
            for (int s = 0; s < 4; ++s) {
                const float* p = qptr + s * 16 + h * 8;
                f32x4 f0 = *reinterpret_cast<const f32x4*>(p);
                f32x4 f1 = *reinterpret_cast<const f32x4*>(p + 4);
                #pragma unroll
                for (int jj = 0; jj < 4; ++jj) {
                    qb[s][jj]     = f2bf(f0[jj] * QS);
                    qb[s][4 + jj] = f2bf(f1[jj] * QS);
                }
            }

            auto dma = [&](int kt) {            // 16 KB k-tile, slot kt&3
                const int sl = (kt & 3) * 4096;
                gl_lds16(kt_src + (size_t)kt * 4096 + dma_off, &smem[sl + dma_off]);
                gl_lds16(vt_src + (size_t)kt * 4096 + dma_off, &smem[16384 + sl + dma_off]);
            };

            auto compute = [&](int kt, const unsigned short* kb, const unsigned short* vb) {
                // S^T quadrant = K(wk-half, row-permuted) * Q^T(wq quarter)
                f32x16 st = {};
                #pragma unroll
                for (int s = 0; s < 4; ++s) {
                    bf16x8 kf = ld_frag((const char*)kb + kaddr[s]);
                    st = mfma32(kf, __builtin_bit_cast(bf16x8, qb[s]), st);
                }
                // P = exp2(S^T) (+ causal mask on the 2 diagonal k-tiles)
                float pex[16];
                if (kt >= tdiag) {
                    const int qth = (i0 + wq * 32 + l31) - (kt * 64 + wk * 32 + 8 * h);
                    #pragma unroll
                    for (int rr = 0; rr < 16; ++rr) {
                        const int K0 = (rr & 7) | ((rr & 8) << 1);
                        pex[rr] = fexp2((K0 > qth) ? -3.0e38f : st[rr]);
                    }
                } else {
                    #pragma unroll
                    for (int rr = 0; rr < 16; ++rr)
                        pex[rr] = fexp2(st[rr]);
                }
                // reg order == PV A-layout k order (K row permutation):
                // A slice t = words u[4t..4t+3], kpos = wk*32 + 16t + 8h + (0..7)
                unsigned int u[8];
                #pragma unroll
                for (int g = 0; g < 4; ++g) {
                    u[2 * g]     = pk2bf(pex[4 * g],     pex[4 * g + 1]);
                    u[2 * g + 1] = pk2bf(pex[4 * g + 2], pex[4 * g + 3]);
                }
                // O += P V ; l += P * ones
                #pragma unroll
                for (int t = 0; t < 2; ++t) {
                    uint4 aw = make_uint4(u[4 * t], u[4 * t + 1], u[4 * t + 2], u[4 * t + 3]);
                    bf16x8 pa = __builtin_bit_cast(bf16x8, aw);
                    #pragma unroll
                    for (int dvt = 0; dvt < 2; ++dvt) {
                        bf16x8 bv = ld_frag((const char*)vb + vbase[t] + dvt * 4096);
                        o_acc[dvt] = mfma32(pa, bv, o_acc[dvt]);
                    }
                    lones = mfma32(pa, ones8, lones);
                }
            };

            // prologue: 3 k-tiles of prefetch lead
            dma(kt0);
            if (kt0 + 1 < kt1) dma(kt0 + 1);
            if (kt0 + 2 < kt1) dma(kt0 + 2);

            int kt = kt0;
            while (true) {
                // 4-slot circular pipeline, counted vmcnt (never drains prefetch)
                __builtin_amdgcn_s_barrier();          // all waves done reading slot (kt-1)&3
                __builtin_amdgcn_sched_barrier(0);
                if (kt + 3 < kt1) dma(kt + 3);         // overwrite slot (kt-1)&3
                {
                    const int rem = kt1 - kt;          // tiles incl. kt still to compute
                    if (rem > 3)       asm volatile("s_waitcnt vmcnt(6)" ::: "memory");
                    else if (rem == 3) asm volatile("s_waitcnt vmcnt(4)" ::: "memory");
                    else if (rem == 2) asm volatile("s_waitcnt vmcnt(2)" ::: "memory");
                    else               asm volatile("s_waitcnt vmcnt(0)" ::: "memory");
                }
                __builtin_amdgcn_sched_barrier(0);
                __builtin_amdgcn_s_barrier();          // kt staged data visible to all
                __builtin_amdgcn_sched_barrier(0);
                const int sl = (kt & 3) * 4096;
                compute(kt, &smem[sl], &smem[16384 + sl]);
                if (++kt == kt1) break;
            }
        }

        // ---- cross-wk reduction through the freed k-tile LDS (once per item) ----
        __syncthreads();                           // everyone done with smem
        float* red   = reinterpret_cast<float*>(&smem[0]);   // 8192 f32 = 32 KB
        float* lredX = red + 8192;                           // 128 f32
        if (wk == 1) {
            #pragma unroll
            for (int rr = 0; rr < 16; ++rr) {
                const int qrow = (rr & 3) + 8 * (rr >> 2) + 4 * h;   // 0..31
                #pragma unroll
                for (int dvt = 0; dvt < 2; ++dvt)
                    red[wq * 2048 + qrow * 64 + dvt * 32 + l31] = o_acc[dvt][rr];
                if (l31 == 0) lredX[wq * 32 + qrow] = lones[rr];
            }
        }
        __syncthreads();
        if (wk == 0) {
            if (half < 0) {
                // final: normalize and write O directly
                float* obase = O + ((size_t)b * N_SEQ + i0 + wq * 32) * DIM;
                #pragma unroll
                for (int rr = 0; rr < 16; ++rr) {
                    const int qrow = (rr & 3) + 8 * (rr >> 2) + 4 * h;
                    const float lt = lones[rr] + lredX[wq * 32 + qrow];
                    const float inv = 1.0f / lt;
                    #pragma unroll
                    for (int dvt = 0; dvt < 2; ++dvt) {
                        const float val = o_acc[dvt][rr]
                            + red[wq * 2048 + qrow * 64 + dvt * 32 + l31];
                        obase[qrow * DIM + dvt * 32 + l31] = val * inv;
                    }
                }
            } else {
                // raw additive partial -> workspace (deep tiles 16..31)
                float* po = wsO + (((size_t)(b * 16 + (tt - 16)) * 2 + half) * 8192);
                float* pl = wsL + (((size_t)(b * 16 + (tt - 16)) * 2 + half) * 128);
                #pragma unroll
                for (int rr = 0; rr < 16; ++rr) {
                    const int qrow = (rr & 3) + 8 * (rr >> 2) + 4 * h;
                    const float lt = lones[rr] + lredX[wq * 32 + qrow];
                    #pragma unroll
                    for (int dvt = 0; dvt < 2; ++dvt)
                        po[(wq * 32 + qrow) * 64 + dvt * 32 + l31] = o_acc[dvt][rr]
                            + red[wq * 2048 + qrow * 64 + dvt * 32 + l31];
                    if (l31 == 0) pl[wq * 32 + qrow] = lt;
                }
            }
        }
        // next item's top-of-loop __syncthreads() protects smem reuse
    }
}

// ---- combine split-K partials for deep tiles 16..31 (128 rows each) ----
__global__ __launch_bounds__(256)
void norm_out(const float* __restrict__ wsO, const float* __restrict__ wsL,
              float* __restrict__ O) {
    const int t = 16 + blockIdx.x, b = blockIdx.y;
    const int row = threadIdx.x >> 1;            // 0..127
    const int c0  = (threadIdx.x & 1) * 32;      // 0,32
    const size_t base = (size_t)(b * 16 + (t - 16)) * 2;
    const float* p0 = wsO + base * 8192 + row * 64 + c0;
    const float* p1 = p0 + 8192;
    const float* l  = wsL + base * 128;
    const float inv = 1.0f / (l[row] + l[128 + row]);
    float* o = O + ((size_t)b * N_SEQ + t * 128 + row) * 64 + c0;
    #pragma unroll
    for (int i = 0; i < 32; i += 4) {
        f32x4 a = *reinterpret_cast<const f32x4*>(p0 + i);
        f32x4 c = *reinterpret_cast<const f32x4*>(p1 + i);
        f32x4 v = (a + c) * inv;
        *reinterpret_cast<f32x4*>(o + i) = v;
    }
}

extern "C" void kernel_launch(void* const* d_in, const int* in_sizes, int n_in,
                              void* d_out, int out_size, void* d_ws, size_t ws_size,
                              hipStream_t stream) {
    const float* q = (const float*)d_in[0];
    const float* k = (const float*)d_in[1];
    const float* v = (const float*)d_in[2];
    // d_in[3] = causal mask, analytic (tril) -- not read.
    float* out = (float*)d_out;

    unsigned short* wsK = (unsigned short*)d_ws;
    unsigned short* wsV = wsK + (size_t)16 * 64 * 4096;        // 8 MB each
    float* wsO = (float*)(wsV + (size_t)16 * 64 * 4096);       // 16.8 MB
    float* wsL = wsO + (size_t)16 * 16 * 2 * 8192;             // 0.26 MB

    prep_kv<<<dim3(64, 16, 2), dim3(256), 0, stream>>>(k, v, wsK, wsV);
    attn_fwd<<<dim3(512), dim3(512), 0, stream>>>(q, wsK, wsV, out, wsO, wsL);
    norm_out<<<dim3(16, 16), dim3(256), 0, stream>>>(wsO, wsL, out);
}